// Round 4
// baseline (534.163 us; speedup 1.0000x reference)
//
#include <hip/hip_runtime.h>

// VectorQuantizer on MI355X (gfx950)
// z:   [B=128, C=128, H=32, W=32] f32 -> pixel n = b*1024 + hw, channel stride 1024
// emb: [K=256, C=128] f32
// out: [quantized_st 16777216][indices 131072][commit 1][codebook 1] (f32)
//
// Exactness contract (verified absmax=0 in round 2 -- DO NOT CHANGE):
//   d_k = fl( fl(zz - 2*s_k) + ee_k )
//   s_k = sequential fmaf over c ascending; zz = sequential fl(z*z) sum
//
// Round-4 structure: z-row per thread staged in LDS (XOR-swizzled b128),
// e read via per-lane global vector loads (opaque-zero base defeats
// scalarization -> vmcnt path, no SMEM in hot loop).

typedef float f32x4 __attribute__((ext_vector_type(4)));

#define VQ_C      128
#define VQ_K      256
#define VQ_HW     1024
#define VQ_NPIX   131072
#define VQ_QELEMS 16777216
#define TPB       64
#define NBLK      (VQ_NPIX / TPB)   // 2048

// ws layout (floats): [0..255] ee[k]; [256..256+NBLK) per-block loss partials
__global__ void vq_prep(const float* __restrict__ emb, float* __restrict__ ws) {
    int k = threadIdx.x;               // 256 threads
    float s = 0.0f;
#pragma unroll
    for (int c = 0; c < VQ_C; ++c) {
        float e = emb[k * VQ_C + c];
        s = __fadd_rn(s, __fmul_rn(e, e));
    }
    ws[k] = s;
}

__global__ __launch_bounds__(TPB, 1) void vq_main(const float* __restrict__ z,
                                                  const float* __restrict__ emb,
                                                  const float* __restrict__ ws,
                                                  float* __restrict__ partials,
                                                  float* __restrict__ out) {
    __shared__ float z_lds[TPB * VQ_C];   // 32 KB: one 512B row per thread
    const int t  = threadIdx.x;
    const int n  = blockIdx.x * TPB + t;  // pixel id, exact grid
    const int b  = n >> 10;
    const int hw = n & 1023;
    const float* __restrict__ zb = z + (size_t)b * (VQ_C * VQ_HW) + hw;

    // Opaque zero in a VGPR: pointers formed from it are "divergent" to the
    // compiler -> e/ee loads become global_load (vmcnt), never s_load (lgkm).
    int vzero;
    asm volatile("v_mov_b32 %0, 0" : "=v"(vzero));

    // Swizzled byte base of my row: t*512 with 16B-block index XOR (t&7).
    // Own-row b128 at (sbase ^ (cg<<4)) -> 8 distinct 4-bank start groups
    // across the wave -> hits the 8-cycle wave64-b128 floor (no conflicts).
    char* const zl = (char*)z_lds;
    const int sbase = (t << 9) ^ ((t & 7) << 4);

    // ---- stage own z row: 4 c-strided coalesced dword loads -> 1 swizzled b128 write
#pragma unroll
    for (int cg = 0; cg < 32; ++cg) {
        f32x4 v;
        v[0] = zb[(cg * 4 + 0) * VQ_HW];
        v[1] = zb[(cg * 4 + 1) * VQ_HW];
        v[2] = zb[(cg * 4 + 2) * VQ_HW];
        v[3] = zb[(cg * 4 + 3) * VQ_HW];
        *(f32x4*)(zl + (sbase ^ (cg << 4))) = v;
    }
    // no __syncthreads: every thread touches only its own LDS row

    // ---- zz: sequential mul-then-add, c ascending (reference order)
    float zz = 0.0f;
#pragma unroll
    for (int cg = 0; cg < 32; ++cg) {
        f32x4 v = *(const f32x4*)(zl + (sbase ^ (cg << 4)));
#pragma unroll
        for (int j = 0; j < 4; ++j) zz = __fadd_rn(zz, __fmul_rn(v[j], v[j]));
    }

    float dmin = INFINITY;
    int   imin = 0;

    const float* __restrict__ e0 = emb + vzero;   // vector-load base
    const float* __restrict__ w0 = ws + vzero;

#pragma unroll 1
    for (int k0 = 0; k0 < VQ_K; k0 += 8) {
        const float* __restrict__ ec = e0 + k0 * VQ_C;  // one v_add per chunk
        float acc[8];
#pragma unroll
        for (int kk = 0; kk < 8; ++kk) acc[kk] = 0.0f;

#pragma unroll
        for (int cg = 0; cg < 32; ++cg) {
            f32x4 zv = *(const f32x4*)(zl + (sbase ^ (cg << 4)));
#pragma unroll
            for (int kk = 0; kk < 8; ++kk) {
                // imm offset = kk*512 + cg*16 bytes <= 4080 (13-bit signed ok)
                f32x4 ev = *(const f32x4*)(ec + kk * VQ_C + cg * 4);
#pragma unroll
                for (int j = 0; j < 4; ++j)
                    acc[kk] = fmaf(zv[j], ev[j], acc[kk]);   // c ascending, exact
            }
        }

        f32x4 eeA = *(const f32x4*)(w0 + k0);
        f32x4 eeB = *(const f32x4*)(w0 + k0 + 4);
#pragma unroll
        for (int kk = 0; kk < 8; ++kk) {
            float eek = (kk < 4) ? eeA[kk] : eeB[kk - 4];
            float d = __fadd_rn(__fsub_rn(zz, __fadd_rn(acc[kk], acc[kk])), eek);
            if (d < dmin) { dmin = d; imin = k0 + kk; }   // strict <: first index wins
        }
    }

    // ---- epilogue: gather e[imin], write quantized_st, accumulate loss
    const f32x4* __restrict__ eq4 = (const f32x4*)(emb + (size_t)imin * VQ_C);
    float* __restrict__ op = out + (size_t)b * (VQ_C * VQ_HW) + hw;
    float lsum = 0.0f;
#pragma unroll
    for (int cg = 0; cg < 32; ++cg) {
        f32x4 q  = eq4[cg];                                   // divergent L2 gather
        f32x4 zv = *(const f32x4*)(zl + (sbase ^ (cg << 4))); // same bits as input z
#pragma unroll
        for (int j = 0; j < 4; ++j) {
            float diff = __fsub_rn(q[j], zv[j]);
            op[(cg * 4 + j) * VQ_HW] = __fadd_rn(zv[j], diff); // coalesced per c
            lsum = fmaf(diff, diff, lsum);
        }
    }
    out[VQ_QELEMS + n] = (float)imin;

    // single-wave block: shuffle reduce, lane 0 writes the partial
#pragma unroll
    for (int off = 32; off > 0; off >>= 1) lsum += __shfl_down(lsum, off, 64);
    if (t == 0) partials[blockIdx.x] = lsum;
}

__global__ void vq_fin(const float* __restrict__ partials, float* __restrict__ out) {
    double acc = 0.0;
    for (int i = 0; i < NBLK; ++i) acc += (double)partials[i];
    float m = (float)(acc * (1.0 / (double)VQ_QELEMS));
    out[VQ_QELEMS + VQ_NPIX + 0] = 0.25f * m;  // commitment
    out[VQ_QELEMS + VQ_NPIX + 1] = m;          // codebook
}

extern "C" void kernel_launch(void* const* d_in, const int* in_sizes, int n_in,
                              void* d_out, int out_size, void* d_ws, size_t ws_size,
                              hipStream_t stream) {
    const float* z   = (const float*)d_in[0];
    const float* emb = (const float*)d_in[1];
    float* out = (float*)d_out;
    float* ws  = (float*)d_ws;            // [0..255]=ee, [256..]=partials

    vq_prep<<<1, 256, 0, stream>>>(emb, ws);
    vq_main<<<NBLK, TPB, 0, stream>>>(z, emb, ws, ws + 256, out);
    vq_fin<<<1, 1, 0, stream>>>(ws + 256, out);
}

// Round 5
// 486.530 us; speedup vs baseline: 1.0979x; 1.0979x over previous
//
#include <hip/hip_runtime.h>

// VectorQuantizer on MI355X (gfx950)
// z:   [B=128, C=128, H=32, W=32] f32 -> pixel n = b*1024 + hw, channel stride 1024
// emb: [K=256, C=128] f32
// out: [quantized_st 16777216][indices 131072][commit 1][codebook 1] (f32)
//
// Exactness contract (verified absmax=0 in round 2 -- DO NOT CHANGE):
//   d_k = fl( fl(zz - 2*s_k) + ee_k )
//   s_k = sequential fmaf over c ascending; zz = sequential fl(z*z) sum
//   k ascending, strict < keeps first-occurrence argmin
//
// Round-5 structure: KK=32 accumulators per thread (8 z-sweeps instead of 32),
// z re-read per chunk as lane-coalesced scalar dwords (L2/L3-hot),
// e via wave-uniform s_load (SGPR broadcast), 32-deep FMA ILP.

typedef float f32x4 __attribute__((ext_vector_type(4)));

#define VQ_C      128
#define VQ_K      256
#define VQ_HW     1024
#define VQ_NPIX   131072
#define VQ_QELEMS 16777216
#define VQ_NBLK   512
#define KK        32            // k's per chunk (accumulators)

// ws layout (floats): [0..255] ee[k]; [256..768) per-block loss partials
__global__ void vq_prep(const float* __restrict__ emb, float* __restrict__ ws) {
    int k = threadIdx.x;               // 256 threads
    float s = 0.0f;
#pragma unroll
    for (int c = 0; c < VQ_C; ++c) {
        float e = emb[k * VQ_C + c];
        s = __fadd_rn(s, __fmul_rn(e, e));
    }
    ws[k] = s;
}

__global__ __launch_bounds__(256, 2) void vq_main(const float* __restrict__ z,
                                                  const float* __restrict__ emb,
                                                  const float* __restrict__ ee,
                                                  float* __restrict__ partials,
                                                  float* __restrict__ out) {
    const int n  = blockIdx.x * 256 + threadIdx.x;   // pixel id, exact grid
    const int b  = n >> 10;
    const int hw = n & 1023;
    const float* __restrict__ zb = z + (size_t)b * (VQ_C * VQ_HW) + hw;

    float zz   = 0.0f;
    float dmin = INFINITY;
    int   imin = 0;

#pragma unroll 1
    for (int k0 = 0; k0 < VQ_K; k0 += KK) {          // 8 chunks
        float acc[KK];
#pragma unroll
        for (int kk = 0; kk < KK; ++kk) acc[kk] = 0.0f;

#pragma unroll 2
        for (int cg = 0; cg < VQ_C / 4; ++cg) {      // 32 c-groups
            // z reload: 4 lane-coalesced dword loads (stride 4KB, L2/L3-hot)
            float z0 = zb[(cg * 4 + 0) * VQ_HW];
            float z1 = zb[(cg * 4 + 1) * VQ_HW];
            float z2 = zb[(cg * 4 + 2) * VQ_HW];
            float z3 = zb[(cg * 4 + 3) * VQ_HW];

            if (k0 == 0) {   // fuse zz into first chunk's sweep (c ascending)
                zz = __fadd_rn(zz, __fmul_rn(z0, z0));
                zz = __fadd_rn(zz, __fmul_rn(z1, z1));
                zz = __fadd_rn(zz, __fmul_rn(z2, z2));
                zz = __fadd_rn(zz, __fmul_rn(z3, z3));
            }

#pragma unroll
            for (int kk = 0; kk < KK; ++kk) {
                // emb index wave-uniform -> s_load_dwordx4; v_fmac v, s, v
                const float* __restrict__ er = emb + (k0 + kk) * VQ_C + cg * 4;
                acc[kk] = fmaf(z0, er[0], acc[kk]);  // c ascending, exact
                acc[kk] = fmaf(z1, er[1], acc[kk]);
                acc[kk] = fmaf(z2, er[2], acc[kk]);
                acc[kk] = fmaf(z3, er[3], acc[kk]);
            }
        }

        // selection after chunk's full c-sweep; zz complete (chunk 0 fused it)
#pragma unroll
        for (int kk = 0; kk < KK; ++kk) {
            float d = __fadd_rn(__fsub_rn(zz, __fadd_rn(acc[kk], acc[kk])), ee[k0 + kk]);
            if (d < dmin) { dmin = d; imin = k0 + kk; }
        }
    }

    // ---- epilogue: gather e[imin], write quantized_st, accumulate loss
    const f32x4* __restrict__ eq4 = (const f32x4*)(emb + (size_t)imin * VQ_C);
    float* __restrict__ op = out + (size_t)b * (VQ_C * VQ_HW) + hw;
    float lsum = 0.0f;
#pragma unroll 4
    for (int cg = 0; cg < VQ_C / 4; ++cg) {
        f32x4 q = eq4[cg];                            // divergent L2 gather
#pragma unroll
        for (int j = 0; j < 4; ++j) {
            int c = cg * 4 + j;
            float zv   = zb[c * VQ_HW];               // L2-hot reload, exact bits
            float diff = __fsub_rn(q[j], zv);
            op[c * VQ_HW] = __fadd_rn(zv, diff);      // coalesced per c
            lsum = fmaf(diff, diff, lsum);
        }
    }
    out[VQ_QELEMS + n] = (float)imin;

    // Deterministic block reduction -> per-block partial
    __shared__ float red[4];
    const int lane = threadIdx.x & 63;
    const int wid  = threadIdx.x >> 6;
#pragma unroll
    for (int off = 32; off > 0; off >>= 1) lsum += __shfl_down(lsum, off, 64);
    if (lane == 0) red[wid] = lsum;
    __syncthreads();
    if (threadIdx.x == 0)
        partials[blockIdx.x] = (red[0] + red[1]) + (red[2] + red[3]);
}

__global__ void vq_fin(const float* __restrict__ partials, float* __restrict__ out) {
    double acc = 0.0;
    for (int i = 0; i < VQ_NBLK; ++i) acc += (double)partials[i];
    float m = (float)(acc * (1.0 / (double)VQ_QELEMS));
    out[VQ_QELEMS + VQ_NPIX + 0] = 0.25f * m;  // commitment
    out[VQ_QELEMS + VQ_NPIX + 1] = m;          // codebook
}

extern "C" void kernel_launch(void* const* d_in, const int* in_sizes, int n_in,
                              void* d_out, int out_size, void* d_ws, size_t ws_size,
                              hipStream_t stream) {
    const float* z   = (const float*)d_in[0];
    const float* emb = (const float*)d_in[1];
    float* out = (float*)d_out;
    float* ws  = (float*)d_ws;            // [0..255]=ee, [256..768)=partials

    vq_prep<<<1, 256, 0, stream>>>(emb, ws);
    vq_main<<<VQ_NBLK, 256, 0, stream>>>(z, emb, ws, ws + 256, out);
    vq_fin<<<1, 1, 0, stream>>>(ws + 256, out);
}

// Round 6
// 223.777 us; speedup vs baseline: 2.3870x; 2.1742x over previous
//
#include <hip/hip_runtime.h>

// VectorQuantizer on MI355X (gfx950)
// z:   [B=128, C=128, H=32, W=32] f32 -> pixel n = b*1024 + hw, channel stride 1024
// emb: [K=256, C=128] f32
// out: [quantized_st 16777216][indices 131072][commit 1][codebook 1] (f32)
//
// Exactness contract (verified absmax=0 in rounds 2-5 -- DO NOT CHANGE):
//   d_k = fl( fl(zz - 2*s_k) + ee_k )
//   s_k = sequential fmaf over c ascending; zz = sequential fl(z*z) sum
//   k ascending, strict < keeps first-occurrence argmin
//
// Round-6 structure: K-split 2 threads/pixel (128 k's each) -> 4096 waves
// (4/SIMD resident). KK=16 accumulators, round-2-proven unroll shape
// (kk-outer, contiguous-c fmaf runs, constant indices only). z staged through
// an explicit 32-float register chunk per c-quarter. Halves merge via LDS.

typedef float f32x4 __attribute__((ext_vector_type(4)));

#define VQ_C      128
#define VQ_K      256
#define VQ_HW     1024
#define VQ_NPIX   131072
#define VQ_QELEMS 16777216
#define PXB       128                 // pixels per block
#define VQ_NBLK   (VQ_NPIX / PXB)     // 1024
#define KK        16                  // k's per chunk (accumulators)

// ws layout (floats): [0..255] ee[k]; [256..256+VQ_NBLK) per-block loss partials
__global__ void vq_prep(const float* __restrict__ emb, float* __restrict__ ws) {
    int k = threadIdx.x;               // 256 threads
    float s = 0.0f;
#pragma unroll
    for (int c = 0; c < VQ_C; ++c) {
        float e = emb[k * VQ_C + c];
        s = __fadd_rn(s, __fmul_rn(e, e));
    }
    ws[k] = s;
}

__global__ __launch_bounds__(256, 4) void vq_main(const float* __restrict__ z,
                                                  const float* __restrict__ emb,
                                                  const float* __restrict__ ee,
                                                  float* __restrict__ partials,
                                                  float* __restrict__ out) {
    const int t   = threadIdx.x;
    const int n   = blockIdx.x * PXB + (t & (PXB - 1));   // pixel id
    // k-half: wave-uniform (waves 0,1 -> half 0; waves 2,3 -> half 1).
    // readfirstlane pins it in an SGPR so all e/ee accesses scalarize.
    const int kbase = __builtin_amdgcn_readfirstlane((t >> 7) * 128);
    const int b   = n >> 10;
    const int hw  = n & 1023;
    const float* __restrict__ zb = z + (size_t)b * (VQ_C * VQ_HW) + hw;

    float zz   = 0.0f;
    float dmin = INFINITY;
    int   imin = 0;

#pragma unroll 1
    for (int k0 = 0; k0 < 128; k0 += KK) {       // 8 chunks of 16 k's
        float acc[KK];
#pragma unroll
        for (int kk = 0; kk < KK; ++kk) acc[kk] = 0.0f;

#pragma unroll 1
        for (int cg = 0; cg < 4; ++cg) {         // c-quarters of 32
            float zc[32];
#pragma unroll
            for (int j = 0; j < 32; ++j) zc[j] = zb[(cg * 32 + j) * VQ_HW];

            if (k0 == 0) {                       // fuse zz into first chunk (c ascending)
#pragma unroll
                for (int j = 0; j < 32; ++j)
                    zz = __fadd_rn(zz, __fmul_rn(zc[j], zc[j]));
            }

#pragma unroll
            for (int kk = 0; kk < KK; ++kk) {    // round-2-proven shape
                const float* __restrict__ er = emb + (kbase + k0 + kk) * VQ_C + cg * 32;
#pragma unroll
                for (int j = 0; j < 32; ++j)
                    acc[kk] = fmaf(zc[j], er[j], acc[kk]);   // c ascending, exact
            }
        }

#pragma unroll
        for (int kk = 0; kk < KK; ++kk) {
            float d = __fadd_rn(__fsub_rn(zz, __fadd_rn(acc[kk], acc[kk])),
                                ee[kbase + k0 + kk]);
            if (d < dmin) { dmin = d; imin = kbase + k0 + kk; }  // strict <
        }
    }

    // ---- merge the two k-halves per pixel via LDS
    __shared__ float dsh[128];
    __shared__ int   ish[128];
    if (t >= 128) { dsh[t - 128] = dmin; ish[t - 128] = imin; }
    __syncthreads();

    float lsum = 0.0f;
    if (t < 128) {
        float d1 = dsh[t];
        int   i1 = ish[t];
        // half-1 index always > half-0 index: strict < keeps first occurrence
        if (d1 < dmin) { dmin = d1; imin = i1; }

        // ---- epilogue: gather e[imin], write quantized_st, accumulate loss
        const f32x4* __restrict__ eq4 = (const f32x4*)(emb + (size_t)imin * VQ_C);
        float* __restrict__ op = out + (size_t)b * (VQ_C * VQ_HW) + hw;
#pragma unroll 4
        for (int cg = 0; cg < VQ_C / 4; ++cg) {
            f32x4 q = eq4[cg];                    // divergent L2 gather
#pragma unroll
            for (int j = 0; j < 4; ++j) {
                int c = cg * 4 + j;
                float zv   = zb[c * VQ_HW];       // L2-hot reload, exact bits
                float diff = __fsub_rn(q[j], zv);
                op[c * VQ_HW] = __fadd_rn(zv, diff);  // coalesced per c
                lsum = fmaf(diff, diff, lsum);
            }
        }
        out[VQ_QELEMS + n] = (float)imin;
    }

    // ---- loss partial: waves 0,1 active-only reduction
    __shared__ float red[2];
#pragma unroll
    for (int off = 32; off > 0; off >>= 1) lsum += __shfl_down(lsum, off, 64);
    if (t < 128 && (t & 63) == 0) red[t >> 6] = lsum;
    __syncthreads();
    if (t == 0) partials[blockIdx.x] = red[0] + red[1];
}

__global__ void vq_fin(const float* __restrict__ partials, float* __restrict__ out) {
    double acc = 0.0;
    for (int i = 0; i < VQ_NBLK; ++i) acc += (double)partials[i];
    float m = (float)(acc * (1.0 / (double)VQ_QELEMS));
    out[VQ_QELEMS + VQ_NPIX + 0] = 0.25f * m;  // commitment
    out[VQ_QELEMS + VQ_NPIX + 1] = m;          // codebook
}

extern "C" void kernel_launch(void* const* d_in, const int* in_sizes, int n_in,
                              void* d_out, int out_size, void* d_ws, size_t ws_size,
                              hipStream_t stream) {
    const float* z   = (const float*)d_in[0];
    const float* emb = (const float*)d_in[1];
    float* out = (float*)d_out;
    float* ws  = (float*)d_ws;            // [0..255]=ee, [256..256+1024)=partials

    vq_prep<<<1, 256, 0, stream>>>(emb, ws);
    vq_main<<<VQ_NBLK, 256, 0, stream>>>(z, emb, ws, ws + 256, out);
    vq_fin<<<1, 1, 0, stream>>>(ws + 256, out);
}

// Round 7
// 220.692 us; speedup vs baseline: 2.4204x; 1.0140x over previous
//
#include <hip/hip_runtime.h>

// VectorQuantizer on MI355X (gfx950)
// z:   [B=128, C=128, H=32, W=32] f32 -> pixel n = b*1024 + hw, channel stride 1024
// emb: [K=256, C=128] f32
// out: [quantized_st 16777216][indices 131072][commit 1][codebook 1] (f32)
//
// Exactness contract (verified absmax=0 rounds 2-6 -- DO NOT CHANGE):
//   d_k = fl( fl(zz - 2*s_k) + ee_k )
//   s_k = sequential fmaf over c ascending; zz = sequential fl(z*z) sum
//   k ascending, first-occurrence argmin (u64 key: d_bits<<32 | k; d > 0 always)
//
// Round-7: z staged ONCE in LDS (padded stride 132 -> ds_read_b128, even
// bank load), 4-way k-split (64 px/block, 256 thr), KK=16 proven unroll shape.
// Kills the 296MB z re-sweep FETCH traffic of round 6.

typedef float f32x4 __attribute__((ext_vector_type(4)));

#define VQ_C      128
#define VQ_K      256
#define VQ_HW     1024
#define VQ_NPIX   131072
#define VQ_QELEMS 16777216
#define PXB       64                  // pixels per block
#define NBLK      (VQ_NPIX / PXB)     // 2048
#define KK        16                  // accumulators per chunk
#define KPQ       64                  // k's per thread (4-way split)
#define LROW      132                 // LDS row stride in floats (528B, 16B-mult)

// ws layout (floats): [0..255] ee[k]; [256..256+NBLK) per-block loss partials
__global__ void vq_prep(const float* __restrict__ emb, float* __restrict__ ws) {
    int k = threadIdx.x;               // 256 threads
    float s = 0.0f;
#pragma unroll
    for (int c = 0; c < VQ_C; ++c) {
        float e = emb[k * VQ_C + c];
        s = __fadd_rn(s, __fmul_rn(e, e));
    }
    ws[k] = s;
}

__global__ __launch_bounds__(256, 4) void vq_main(const float* __restrict__ z,
                                                  const float* __restrict__ emb,
                                                  const float* __restrict__ ee,
                                                  float* __restrict__ partials,
                                                  float* __restrict__ out) {
    __shared__ float              zf[PXB * LROW];   // 33792 B, padded rows
    __shared__ unsigned long long key[4 * PXB];     // 2048 B merge keys
    __shared__ float              red[4];

    const int t  = threadIdx.x;
    const int p  = t & 63;                     // pixel-in-block == lane
    const int q  = t >> 6;                     // wave id == k-quarter
    const int kbase = __builtin_amdgcn_readfirstlane(q * KPQ);
    const int n  = blockIdx.x * PXB + p;       // 64 | 1024 -> no b straddle
    const int b  = n >> 10;
    const int hw = n & 1023;
    const float* __restrict__ zb = z + (size_t)b * (VQ_C * VQ_HW) + hw;

    // ---- stage z once: wave q loads c = q+4i (coalesced 256B per instr)
#pragma unroll
    for (int i = 0; i < 32; ++i) {
        int c = q + 4 * i;
        zf[p * LROW + c] = zb[c * VQ_HW];
    }
    __syncthreads();

    const f32x4* __restrict__ z4 = (const f32x4*)zf;   // index p*33 + cg

    float zz   = 0.0f;
    float dmin = INFINITY;
    int   imin = 0;

#pragma unroll 1
    for (int k0 = 0; k0 < KPQ; k0 += KK) {     // 4 chunks of 16 k's
        float acc[KK];
#pragma unroll
        for (int kk = 0; kk < KK; ++kk) acc[kk] = 0.0f;

#pragma unroll 1
        for (int cg = 0; cg < 32; ++cg) {      // 4 c's per iter, ds_read_b128
            f32x4 zv = z4[p * 33 + cg];

            if (k0 == 0) {                     // fold zz into chunk 0, c ascending
                zz = __fadd_rn(zz, __fmul_rn(zv[0], zv[0]));
                zz = __fadd_rn(zz, __fmul_rn(zv[1], zv[1]));
                zz = __fadd_rn(zz, __fmul_rn(zv[2], zv[2]));
                zz = __fadd_rn(zz, __fmul_rn(zv[3], zv[3]));
            }

#pragma unroll
            for (int kk = 0; kk < KK; ++kk) {  // e wave-uniform -> s_load_dwordx4
                const float* __restrict__ er = emb + (kbase + k0 + kk) * VQ_C + cg * 4;
                acc[kk] = fmaf(zv[0], er[0], acc[kk]);   // c ascending, exact
                acc[kk] = fmaf(zv[1], er[1], acc[kk]);
                acc[kk] = fmaf(zv[2], er[2], acc[kk]);
                acc[kk] = fmaf(zv[3], er[3], acc[kk]);
            }
        }

#pragma unroll
        for (int kk = 0; kk < KK; ++kk) {
            float d = __fadd_rn(__fsub_rn(zz, __fadd_rn(acc[kk], acc[kk])),
                                ee[kbase + k0 + kk]);
            if (d < dmin) { dmin = d; imin = kbase + k0 + kk; }  // strict <
        }
    }

    // ---- 4-way merge via u64 key (d>0 so bit order == float order;
    //      equal d -> lower index wins == first occurrence)
    union { float f; unsigned u; } du; du.f = dmin;
    key[q * PXB + p] = ((unsigned long long)du.u << 32) | (unsigned)imin;
    __syncthreads();
    unsigned long long kf = key[p];
#pragma unroll
    for (int j = 1; j < 4; ++j) {
        unsigned long long kj = key[j * PXB + p];
        if (kj < kf) kf = kj;
    }
    const int ifin = (int)(kf & 0xffffffffu);

    // ---- epilogue, c-split across q: thread (p,q) handles c in [q*32, q*32+32)
    const float* __restrict__ eq = emb + (size_t)ifin * VQ_C + q * 32;
    float* __restrict__ op = out + (size_t)b * (VQ_C * VQ_HW) + hw;
    float lsum = 0.0f;
#pragma unroll
    for (int cg = 0; cg < 8; ++cg) {
        f32x4 e4 = *(const f32x4*)(eq + cg * 4);       // divergent L2 gather
        f32x4 zv = z4[p * 33 + (q * 8 + cg)];          // exact z bits from LDS
#pragma unroll
        for (int j = 0; j < 4; ++j) {
            int c = q * 32 + cg * 4 + j;
            float diff = __fsub_rn(e4[j], zv[j]);
            op[c * VQ_HW] = __fadd_rn(zv[j], diff);    // coalesced per c
            lsum = fmaf(diff, diff, lsum);
        }
    }
    if (q == 0) out[VQ_QELEMS + n] = (float)ifin;

    // ---- loss partial: block reduce (grouping change only affects loss
    //      rounding at ~1e-7 -- far below threshold)
#pragma unroll
    for (int off = 32; off > 0; off >>= 1) lsum += __shfl_down(lsum, off, 64);
    if ((t & 63) == 0) red[t >> 6] = lsum;
    __syncthreads();
    if (t == 0)
        partials[blockIdx.x] = (red[0] + red[1]) + (red[2] + red[3]);
}

__global__ void vq_fin(const float* __restrict__ partials, float* __restrict__ out) {
    double acc = 0.0;
    for (int i = 0; i < NBLK; ++i) acc += (double)partials[i];
    float m = (float)(acc * (1.0 / (double)VQ_QELEMS));
    out[VQ_QELEMS + VQ_NPIX + 0] = 0.25f * m;  // commitment
    out[VQ_QELEMS + VQ_NPIX + 1] = m;          // codebook
}

extern "C" void kernel_launch(void* const* d_in, const int* in_sizes, int n_in,
                              void* d_out, int out_size, void* d_ws, size_t ws_size,
                              hipStream_t stream) {
    const float* z   = (const float*)d_in[0];
    const float* emb = (const float*)d_in[1];
    float* out = (float*)d_out;
    float* ws  = (float*)d_ws;            // [0..255]=ee, [256..256+2048)=partials

    vq_prep<<<1, 256, 0, stream>>>(emb, ws);
    vq_main<<<NBLK, 256, 0, stream>>>(z, emb, ws, ws + 256, out);
    vq_fin<<<1, 1, 0, stream>>>(ws + 256, out);
}